// Round 4
// baseline (259.242 us; speedup 1.0000x reference)
//
#include <hip/hip_runtime.h>
#include <hip/hip_bf16.h>

typedef __attribute__((ext_vector_type(8))) __bf16 bf16x8;
typedef __attribute__((ext_vector_type(4))) float f32x4;
typedef unsigned short u16;
typedef unsigned int u32;

#define NB 8192
#define ND 128
#define NBLK 2080
#define NEGINF (-__builtin_inff())
#define POSINF (__builtin_inff())
#define ENC_NEGINF 0x007FFFFFu   // encf(-inf)
#define ENC_POSINF 0xFF800000u   // encf(+inf)

__device__ inline u16 f2b(float f){
  __hip_bfloat16 h = __float2bfloat16(f);
  return *reinterpret_cast<u16*>(&h);
}
// monotone float <-> uint encoding (order-preserving incl. +-inf)
__device__ inline u32 encf(float f){
  u32 b = __float_as_uint(f);
  return b ^ (0x80000000u | (u32)(((int)b) >> 31));
}
__device__ inline float decf(u32 u){
  return __uint_as_float(u ^ (0x80000000u | (u32)((~(int)u) >> 31)));
}
__device__ inline f32x4 mfma16(bf16x8 a, bf16x8 b, f32x4 c){
  return __builtin_amdgcn_mfma_f32_16x16x32_bf16(a, b, c, 0, 0, 0);
}

// ---- sort: single block; class histogram -> prefix -> scatter permutation --
extern "C" __global__ __launch_bounds__(256)
void sort_k(const int* __restrict__ lab, int* __restrict__ srcOf,
            u32* __restrict__ tileCls)
{
  __shared__ u32 hist[256], scan[256], startB[256], cnt[256];
  __shared__ u16 clsS[NB];
  const int t = threadIdx.x;
  hist[t] = 0; cnt[t] = 0;
  __syncthreads();
  for (int r = t; r < NB; r += 256) atomicAdd(&hist[lab[r]], 1u);
  __syncthreads();
  scan[t] = hist[t];
  __syncthreads();
  #pragma unroll
  for (int off = 1; off < 256; off <<= 1){
    u32 add = (t >= off) ? scan[t - off] : 0u;
    __syncthreads();
    scan[t] += add;
    __syncthreads();
  }
  startB[t] = scan[t] - hist[t];   // exclusive prefix
  __syncthreads();
  for (int r = t; r < NB; r += 256){
    const int c = lab[r];
    const u32 pos = startB[c] + atomicAdd(&cnt[c], 1u);
    srcOf[pos] = r;
    clsS[pos] = (u16)c;
  }
  __syncthreads();
  if (t < 64)
    tileCls[t] = (u32)clsS[t * 128] | ((u32)clsS[t * 128 + 127] << 16);
}

// ---- prep: gather-sorted fp32->bf16, colp=(sq,p,sq*p,lab); init atomics ----
extern "C" __global__ __launch_bounds__(256)
void prep_k(const float* __restrict__ x, const int* __restrict__ lab,
            const int* __restrict__ srcOf,
            u16* __restrict__ xb, float4* __restrict__ colp,
            u32* __restrict__ ppos, u32* __restrict__ pneg,
            u32* __restrict__ done)
{
  const int R0 = blockIdx.x * 128;     // 64 blocks
  const int rr  = threadIdx.x >> 5;    // 8 rows per pass
  const int sub = threadIdx.x & 31;
  for (int it = 0; it < 16; ++it){
    const int s   = R0 + it * 8 + rr;
    const int src = srcOf[s];
    const float4 v = reinterpret_cast<const float4*>(x)[src * 32 + sub];
    float ss = v.x*v.x + v.y*v.y + v.z*v.z + v.w*v.w;
    #pragma unroll
    for (int m = 1; m < 32; m <<= 1) ss += __shfl_xor(ss, m, 32);
    ushort4 o;
    o.x = f2b(v.x); o.y = f2b(v.y); o.z = f2b(v.z); o.w = f2b(v.w);
    reinterpret_cast<ushort4*>(xb)[s * 32 + sub] = o;
    if (sub == 0){
      const float p = 1.0f / (1.0f - ss);
      colp[s] = make_float4(ss, p, ss * p, __int_as_float(lab[src]));
    }
  }
  if (threadIdx.x < 128) ppos[R0 + threadIdx.x] = ENC_NEGINF;
  else                   pneg[R0 + threadIdx.x - 128] = ENC_POSINF;
  if (blockIdx.x == 0 && threadIdx.x == 0) *done = 0u;
}

// ---- main: triangular 128x128 tiles, sorted classes, fused finalize --------
extern "C" __global__ __launch_bounds__(256, 3)
void gram_k(const u16* __restrict__ xb, const float4* __restrict__ colp,
            const u32* __restrict__ tileCls,
            u32* __restrict__ ppos, u32* __restrict__ pneg,
            u32* __restrict__ done, float* __restrict__ out)
{
  __shared__ u16 Bt[128 * 128];   // 32 KB; 16B chunks XOR-swizzled by row&15
  __shared__ u32 s_last;
  const int wid  = threadIdx.x >> 6;
  const int lane = threadIdx.x & 63;
  const int m16  = lane & 15;
  const int quad = lane >> 4;

  // triangular decode: g(b)=b*(129-b)/2
  int idx = (int)blockIdx.x;
  int bi0 = (int)((129.0f - sqrtf((float)(16641 - 8 * idx))) * 0.5f);
  while ((bi0 + 1) * (129 - (bi0 + 1)) / 2 <= idx) ++bi0;
  while (bi0 * (129 - bi0) / 2 > idx) --bi0;
  const int bi = __builtin_amdgcn_readfirstlane(bi0);
  const int bj = __builtin_amdgcn_readfirstlane(bi0 + (idx - bi0 * (129 - bi0) / 2));
  const int C0  = bj * 128;
  const int WR0 = bi * 128 + wid * 32;
  const u32 tci = tileCls[bi], tcj = tileCls[bj];
  const bool fat = ((tci >> 16) >= (tcj & 0xFFFFu));  // class ranges overlap

  // stage B tile: LDS chunk p of row j <- global chunk p^(j&15)
  #pragma unroll
  for (int c = 0; c < 8; ++c){
    const int cc   = wid * 8 + c;
    const int brow = cc * 4 + quad;
    const int src  = m16 ^ (brow & 15);
    const u16* gsrc = xb + (C0 + brow) * ND + src * 8;
    __builtin_amdgcn_global_load_lds(
        (const __attribute__((address_space(1))) void*)gsrc,
        (__attribute__((address_space(3))) void*)(Bt + cc * 512), 16, 0, 0);
  }

  // A fragments in registers: A[m=lane&15][k=quad*8+j]
  bf16x8 afrag[2][4];
  #pragma unroll
  for (int mt = 0; mt < 2; ++mt){
    const u16* arow = xb + (WR0 + mt*16 + m16) * ND;
    #pragma unroll
    for (int ks = 0; ks < 4; ++ks)
      afrag[mt][ks] = *reinterpret_cast<const bf16x8*>(arow + ks*32 + quad*8);
  }

  // per-row params (C/D row = quad*4 + r)
  float sqi[8], pi[8];
  #pragma unroll
  for (int mt = 0; mt < 2; ++mt)
    #pragma unroll
    for (int r = 0; r < 4; ++r){
      const float4 cp = colp[WR0 + mt*16 + quad*4 + r];
      sqi[mt*4+r] = cp.x;
      pi[mt*4+r]  = cp.y;
    }

  __syncthreads();

  if (!fat){
    // ---------------- LEAN: no same-label pair possible; neg-only ----------
    float vneg[8], cneg[8];
    #pragma unroll
    for (int i = 0; i < 8; ++i){ vneg[i] = POSINF; cneg[i] = POSINF; }

    #pragma unroll
    for (int half = 0; half < 2; ++half){
      float4 cpv[4];
      #pragma unroll
      for (int nt4 = 0; nt4 < 4; ++nt4)
        cpv[nt4] = colp[C0 + (half*4 + nt4)*16 + m16];
      f32x4 acc[2][4];
      #pragma unroll
      for (int mt = 0; mt < 2; ++mt)
        #pragma unroll
        for (int nt4 = 0; nt4 < 4; ++nt4){
          f32x4 z = {0.f,0.f,0.f,0.f};
          acc[mt][nt4] = z;
        }
      #pragma unroll
      for (int ks = 0; ks < 4; ++ks){
        const int t = ks * 4 + quad;
        #pragma unroll
        for (int nt4 = 0; nt4 < 4; ++nt4){
          const int nt = half*4 + nt4;
          const bf16x8 bfrag = *reinterpret_cast<const bf16x8*>(
              Bt + (nt*16 + m16) * 128 + ((t ^ m16) * 8));
          acc[0][nt4] = mfma16(afrag[0][ks], bfrag, acc[0][nt4]);
          acc[1][nt4] = mfma16(afrag[1][ks], bfrag, acc[1][nt4]);
        }
      }
      #pragma unroll
      for (int nt4 = 0; nt4 < 4; ++nt4){
        const int nt = half*4 + nt4;
        const float sqj = cpv[nt4].x, pj = cpv[nt4].y;
        #pragma unroll
        for (int mt = 0; mt < 2; ++mt)
          #pragma unroll
          for (int r = 0; r < 4; ++r){
            const int i = mt*4 + r;
            const float d2 = fmaf(-2.0f, acc[mt][nt4][r], sqi[i] + sqj);
            vneg[i]  = fminf(vneg[i],  d2 * pj);
            cneg[nt] = fminf(cneg[nt], d2 * pi[i]);
          }
      }
    }
    #pragma unroll
    for (int i = 0; i < 8; ++i)
      #pragma unroll
      for (int m = 1; m < 16; m <<= 1)
        vneg[i] = fminf(vneg[i], __shfl_xor(vneg[i], m, 16));
    if (m16 == 0){
      #pragma unroll
      for (int i = 0; i < 8; ++i){
        const int row = WR0 + (i >> 2)*16 + quad*4 + (i & 3);
        atomicMin(pneg + row, encf(vneg[i]));
      }
    }
    #pragma unroll
    for (int nt = 0; nt < 8; ++nt){
      cneg[nt] = fminf(cneg[nt], __shfl_xor(cneg[nt], 16));
      cneg[nt] = fminf(cneg[nt], __shfl_xor(cneg[nt], 32));
    }
    float* cbN = reinterpret_cast<float*>(Bt);
    __syncthreads();
    if (quad == 0){
      #pragma unroll
      for (int nt = 0; nt < 8; ++nt)
        cbN[wid*128 + nt*16 + m16] = cneg[nt];
    }
    __syncthreads();
    if (threadIdx.x < 128){
      const int c = threadIdx.x;
      float N = POSINF;
      #pragma unroll
      for (int w = 0; w < 4; ++w) N = fminf(N, cbN[w*128 + c]);
      atomicMin(pneg + C0 + c, encf(N));
    }
  } else {
    // ---------------- FAT: label-masked pos/neg (band tiles only) ----------
    const bool diag = (bi == bj);
    int labi[8];
    const float* colpF = reinterpret_cast<const float*>(colp);
    #pragma unroll
    for (int mt = 0; mt < 2; ++mt)
      #pragma unroll
      for (int r = 0; r < 4; ++r)
        labi[mt*4+r] = __float_as_int(colpF[(WR0 + mt*16 + quad*4 + r)*4 + 3]);

    float vpos[8], vneg[8], cpos[8], cneg[8];
    #pragma unroll
    for (int i = 0; i < 8; ++i){
      vpos[i] = NEGINF; vneg[i] = POSINF;
      cpos[i] = NEGINF; cneg[i] = POSINF;
    }

    #pragma unroll
    for (int half = 0; half < 2; ++half){
      float4 cpv[4];
      #pragma unroll
      for (int nt4 = 0; nt4 < 4; ++nt4)
        cpv[nt4] = colp[C0 + (half*4 + nt4)*16 + m16];
      f32x4 acc[2][4];
      #pragma unroll
      for (int mt = 0; mt < 2; ++mt)
        #pragma unroll
        for (int nt4 = 0; nt4 < 4; ++nt4){
          f32x4 z = {0.f,0.f,0.f,0.f};
          acc[mt][nt4] = z;
        }
      #pragma unroll
      for (int ks = 0; ks < 4; ++ks){
        const int t = ks * 4 + quad;
        #pragma unroll
        for (int nt4 = 0; nt4 < 4; ++nt4){
          const int nt = half*4 + nt4;
          const bf16x8 bfrag = *reinterpret_cast<const bf16x8*>(
              Bt + (nt*16 + m16) * 128 + ((t ^ m16) * 8));
          acc[0][nt4] = mfma16(afrag[0][ks], bfrag, acc[0][nt4]);
          acc[1][nt4] = mfma16(afrag[1][ks], bfrag, acc[1][nt4]);
        }
      }
      #pragma unroll
      for (int nt4 = 0; nt4 < 4; ++nt4){
        const int nt = half*4 + nt4;
        const float sqj  = cpv[nt4].x;
        const float pj   = cpv[nt4].y;
        const int   labj = __float_as_int(cpv[nt4].w);
        if (!diag){
          #pragma unroll
          for (int mt = 0; mt < 2; ++mt)
            #pragma unroll
            for (int r = 0; r < 4; ++r){
              const int i = mt*4 + r;
              const float d2 = fmaf(-2.0f, acc[mt][nt4][r], sqi[i] + sqj);
              const float ur = d2 * pj;
              const float uc = d2 * pi[i];
              const bool sm = (labi[i] == labj);
              vpos[i]  = fmaxf(vpos[i],  sm ? ur : NEGINF);
              vneg[i]  = fminf(vneg[i],  sm ? POSINF : ur);
              cpos[nt] = fmaxf(cpos[nt], sm ? uc : NEGINF);
              cneg[nt] = fminf(cneg[nt], sm ? POSINF : uc);
            }
        } else {
          const int colin = nt*16 + m16;
          #pragma unroll
          for (int mt = 0; mt < 2; ++mt)
            #pragma unroll
            for (int r = 0; r < 4; ++r){
              const int i = mt*4 + r;
              const float d2 = fmaf(-2.0f, acc[mt][nt4][r], sqi[i] + sqj);
              const float ur = d2 * pj;
              const bool sm = (labi[i] == labj);
              const bool dg = (colin == wid*32 + mt*16 + quad*4 + r);
              float ep = sm ? ur : NEGINF;
              ep = dg ? NEGINF : ep;
              vpos[i] = fmaxf(vpos[i], ep);
              vneg[i] = fminf(vneg[i], sm ? POSINF : ur);
            }
        }
      }
    }
    #pragma unroll
    for (int i = 0; i < 8; ++i)
      #pragma unroll
      for (int m = 1; m < 16; m <<= 1){
        vpos[i] = fmaxf(vpos[i], __shfl_xor(vpos[i], m, 16));
        vneg[i] = fminf(vneg[i], __shfl_xor(vneg[i], m, 16));
      }
    if (m16 == 0){
      #pragma unroll
      for (int i = 0; i < 8; ++i){
        const int row = WR0 + (i >> 2)*16 + quad*4 + (i & 3);
        atomicMax(ppos + row, encf(vpos[i]));
        atomicMin(pneg + row, encf(vneg[i]));
      }
    }
    if (!diag){
      #pragma unroll
      for (int nt = 0; nt < 8; ++nt){
        cpos[nt] = fmaxf(cpos[nt], __shfl_xor(cpos[nt], 16));
        cpos[nt] = fmaxf(cpos[nt], __shfl_xor(cpos[nt], 32));
        cneg[nt] = fminf(cneg[nt], __shfl_xor(cneg[nt], 16));
        cneg[nt] = fminf(cneg[nt], __shfl_xor(cneg[nt], 32));
      }
      float* cbP = reinterpret_cast<float*>(Bt);
      float* cbN = cbP + 512;
      __syncthreads();
      if (quad == 0){
        #pragma unroll
        for (int nt = 0; nt < 8; ++nt){
          cbP[wid*128 + nt*16 + m16] = cpos[nt];
          cbN[wid*128 + nt*16 + m16] = cneg[nt];
        }
      }
      __syncthreads();
      if (threadIdx.x < 128){
        const int c = threadIdx.x;
        float P = NEGINF, N = POSINF;
        #pragma unroll
        for (int w = 0; w < 4; ++w){
          P = fmaxf(P, cbP[w*128 + c]);
          N = fminf(N, cbN[w*128 + c]);
        }
        atomicMax(ppos + C0 + c, encf(P));
        atomicMin(pneg + C0 + c, encf(N));
      }
    }
  }

  // ---------------- fused finalize: last block computes the loss -----------
  __threadfence();
  if (threadIdx.x == 0)
    s_last = (atomicAdd(done, 1u) == (u32)(NBLK - 1)) ? 1u : 0u;
  __syncthreads();
  if (s_last){
    __threadfence();
    float lsum = 0.0f, lcnt = 0.0f;
    for (int r = (int)threadIdx.x; r < NB; r += 256){
      const float up = decf(atomicMax(ppos + r, 0u));          // coherent read
      const float un = decf(atomicMin(pneg + r, 0xFFFFFFFFu)); // coherent read
      const bool hp = (up > NEGINF);
      const bool hn = (un < POSINF);
      const float pr = colp[r].y;
      float dp = 0.0f, dn = 0.0f;
      if (hp){ float t = fmaxf(2.0f * up * pr, 1e-7f); dp = log1pf(t + sqrtf(t * (t + 2.0f))); }
      if (hn){ float t = fmaxf(2.0f * un * pr, 1e-7f); dn = log1pf(t + sqrtf(t * (t + 2.0f))); }
      if (hp && hn){ lsum += fmaxf(dp - dn + 0.5f, 0.0f); lcnt += 1.0f; }
    }
    #pragma unroll
    for (int m = 1; m < 64; m <<= 1){
      lsum += __shfl_xor(lsum, m, 64);
      lcnt += __shfl_xor(lcnt, m, 64);
    }
    float2* sp = reinterpret_cast<float2*>(Bt);
    if ((threadIdx.x & 63) == 0) sp[threadIdx.x >> 6] = make_float2(lsum, lcnt);
    __syncthreads();
    if (threadIdx.x == 0){
      const float S = sp[0].x + sp[1].x + sp[2].x + sp[3].x;
      const float C = sp[0].y + sp[1].y + sp[2].y + sp[3].y;
      out[0] = (C > 0.0f) ? (S / C) : 0.0f;
    }
  }
}

extern "C" void kernel_launch(void* const* d_in, const int* in_sizes, int n_in,
                              void* d_out, int out_size, void* d_ws, size_t ws_size,
                              hipStream_t stream)
{
  const float* x  = (const float*)d_in[0];
  const int* lab  = (const int*)d_in[1];
  char* ws = (char*)d_ws;
  u16*    xb    = (u16*)ws;                                    // 2 MB
  float4* colp  = (float4*)(ws + (size_t)2*1024*1024);         // 128 KB
  u32*    ppos  = (u32*)(ws + (size_t)2*1024*1024 + 128*1024); // 32 KB
  u32*    pneg  = (u32*)(ws + (size_t)2*1024*1024 + 160*1024); // 32 KB
  int*    srcOf = (int*)(ws + (size_t)2*1024*1024 + 192*1024); // 32 KB
  u32*    tileCls = (u32*)(ws + (size_t)2*1024*1024 + 224*1024); // 256 B
  u32*    done  = (u32*)(ws + (size_t)2*1024*1024 + 225*1024);   // 4 B

  hipLaunchKernelGGL(sort_k, dim3(1), dim3(256), 0, stream, lab, srcOf, tileCls);
  hipLaunchKernelGGL(prep_k, dim3(64), dim3(256), 0, stream,
                     x, lab, srcOf, xb, colp, ppos, pneg, done);
  hipLaunchKernelGGL(gram_k, dim3(NBLK), dim3(256), 0, stream,
                     xb, colp, tileCls, ppos, pneg, done, (float*)d_out);
}

// Round 5
// 165.003 us; speedup vs baseline: 1.5711x; 1.5711x over previous
//
#include <hip/hip_runtime.h>
#include <hip/hip_bf16.h>

typedef __attribute__((ext_vector_type(8))) __bf16 bf16x8;
typedef __attribute__((ext_vector_type(4))) float f32x4;
typedef unsigned short u16;
typedef unsigned int u32;

#define NB 8192
#define NBLK 2080
#define NEGINF (-__builtin_inff())
#define POSINF (__builtin_inff())

// monotone float <-> uint encoding (order-preserving incl. +-inf); encf(real) != 0
__device__ inline u32 encf(float f){
  u32 b = __float_as_uint(f);
  return b ^ (0x80000000u | (u32)(((int)b) >> 31));
}
__device__ inline float decf(u32 u){
  return __uint_as_float(u ^ (0x80000000u | (u32)((~(int)u) >> 31)));
}
__device__ inline f32x4 mfma16(bf16x8 a, bf16x8 b, f32x4 c){
  return __builtin_amdgcn_mfma_f32_16x16x32_bf16(a, b, c, 0, 0, 0);
}
__device__ inline ushort4 cvt4(float4 a){
  union { ushort4 s; __hip_bfloat162 h[2]; } u;
  u.h[0] = __float22bfloat162_rn(make_float2(a.x, a.y));
  u.h[1] = __float22bfloat162_rn(make_float2(a.z, a.w));
  return u.s;
}
__device__ inline bf16x8 cvt8(float4 a, float4 b){
  union { bf16x8 v; __hip_bfloat162 h[4]; } u;
  u.h[0] = __float22bfloat162_rn(make_float2(a.x, a.y));
  u.h[1] = __float22bfloat162_rn(make_float2(a.z, a.w));
  u.h[2] = __float22bfloat162_rn(make_float2(b.x, b.y));
  u.h[3] = __float22bfloat162_rn(make_float2(b.z, b.w));
  return u.v;
}

// ---- single fused kernel: per-block fp32->bf16 conversion, triangular tiles,
// atomic merge (sentinel-free: pm holds encf(max w), nm holds ~encf(min w),
// both under atomicMax with memset-0 init), done-counter finalize (NO fences:
// __syncthreads' implicit vmcnt(0) drain orders each wave's atomics before the
// done add; finalize reads via RMW atomics which are coherent by construction).
extern "C" __global__ __launch_bounds__(256, 2)
void fused_k(const float* __restrict__ x, const int* __restrict__ lab,
             u32* __restrict__ pm, u32* __restrict__ nm,
             u32* __restrict__ done, float* __restrict__ out)
{
  __shared__ u16 Bt[128 * 128];   // 32 KB bf16 B-tile; 16B chunks XOR-swizzled by row&15
  __shared__ float sqA[128], pA[128], sqB[128], pB[128];
  __shared__ int labA[128], labB[128];
  __shared__ u32 s_last;
  __shared__ float2 s_fin[4];

  const int tid  = threadIdx.x;
  const int wid  = tid >> 6;
  const int lane = tid & 63;
  const int m16  = lane & 15;
  const int quad = lane >> 4;

  // triangular decode: g(b)=b*(129-b)/2
  int idx = (int)blockIdx.x;
  int bi0 = (int)((129.0f - sqrtf((float)(16641 - 8 * idx))) * 0.5f);
  while ((bi0 + 1) * (129 - (bi0 + 1)) / 2 <= idx) ++bi0;
  while (bi0 * (129 - bi0) / 2 > idx) --bi0;
  const int bi = bi0;
  const int bj = bi0 + (idx - bi0 * (129 - bi0) / 2);
  const bool diag = (bi == bj);
  const int R0 = bi * 128, C0 = bj * 128;
  const int WR0 = R0 + wid * 32;

  // ---- phase 1: row norms for A & B rows; convert B rows to LDS bf16 ------
  const int rr = tid >> 5, sub = tid & 31;
  for (int pp = 0; pp < 16; ++pp){
    const int r = pp * 8 + rr;
    const float4 va = reinterpret_cast<const float4*>(x)[(R0 + r) * 32 + sub];
    float sa = va.x*va.x + va.y*va.y + va.z*va.z + va.w*va.w;
    #pragma unroll
    for (int m = 1; m < 32; m <<= 1) sa += __shfl_xor(sa, m, 32);
    const float4 vb = reinterpret_cast<const float4*>(x)[(C0 + r) * 32 + sub];
    float sb = vb.x*vb.x + vb.y*vb.y + vb.z*vb.z + vb.w*vb.w;
    #pragma unroll
    for (int m = 1; m < 32; m <<= 1) sb += __shfl_xor(sb, m, 32);
    if (sub == 0){
      sqA[r] = sa; pA[r] = 1.0f / (1.0f - sa);
      sqB[r] = sb; pB[r] = 1.0f / (1.0f - sb);
    }
    if (sub == 1) labA[r] = lab[R0 + r];
    if (sub == 2) labB[r] = lab[C0 + r];
    // B-tile LDS write: chunk (sub>>1) goes to swizzled pos (sub>>1)^(r&15)
    reinterpret_cast<ushort4*>(Bt)[r*32 + (((sub>>1) ^ (r & 15)) << 1) + (sub & 1)] = cvt4(vb);
  }

  // A fragments in registers: A[m=lane&15][k=quad*8+j], converted from fp32
  bf16x8 afrag[2][4];
  #pragma unroll
  for (int mt = 0; mt < 2; ++mt){
    const float4* ar = reinterpret_cast<const float4*>(x) + (size_t)(WR0 + mt*16 + m16) * 32;
    #pragma unroll
    for (int ks = 0; ks < 4; ++ks)
      afrag[mt][ks] = cvt8(ar[ks*8 + quad*2], ar[ks*8 + quad*2 + 1]);
  }

  __syncthreads();

  // per-row params (C/D row = quad*4 + r)
  float sqi[8], pi[8]; int labi[8];
  #pragma unroll
  for (int mt = 0; mt < 2; ++mt)
    #pragma unroll
    for (int r = 0; r < 4; ++r){
      const int rl = wid*32 + mt*16 + quad*4 + r;
      sqi[mt*4+r]  = sqA[rl];
      pi[mt*4+r]   = pA[rl];
      labi[mt*4+r] = labA[rl];
    }

  // ---- MFMA ----------------------------------------------------------------
  f32x4 acc[2][8];
  #pragma unroll
  for (int mt = 0; mt < 2; ++mt)
    #pragma unroll
    for (int nt = 0; nt < 8; ++nt){
      f32x4 z = {0.f, 0.f, 0.f, 0.f};
      acc[mt][nt] = z;
    }
  #pragma unroll
  for (int ks = 0; ks < 4; ++ks){
    const int t = ks * 4 + quad;
    #pragma unroll
    for (int nt = 0; nt < 8; ++nt){
      const bf16x8 bfrag = *reinterpret_cast<const bf16x8*>(
          Bt + (nt*16 + m16) * 128 + ((t ^ m16) * 8));
      acc[0][nt] = mfma16(afrag[0][ks], bfrag, acc[0][nt]);
      acc[1][nt] = mfma16(afrag[1][ks], bfrag, acc[1][nt]);
    }
  }

  // ---- epilogue: w = (sq_i+sq_j-2g) * p_i * p_j (symmetric) ----------------
  float vpos[8], vneg[8], cpos[8], cneg[8];
  #pragma unroll
  for (int i = 0; i < 8; ++i){
    vpos[i] = NEGINF; vneg[i] = POSINF;
    cpos[i] = NEGINF; cneg[i] = POSINF;
  }
  #pragma unroll
  for (int nt = 0; nt < 8; ++nt){
    const float sqj  = sqB[nt*16 + m16];
    const float pj   = pB[nt*16 + m16];
    const int   labj = labB[nt*16 + m16];
    if (!diag){
      #pragma unroll
      for (int mt = 0; mt < 2; ++mt)
        #pragma unroll
        for (int r = 0; r < 4; ++r){
          const int i = mt*4 + r;
          const float d2 = fmaf(-2.0f, acc[mt][nt][r], sqi[i] + sqj);
          const float w  = d2 * (pi[i] * pj);
          const bool sm = (labi[i] == labj);
          vpos[i]  = fmaxf(vpos[i],  sm ? w : NEGINF);
          vneg[i]  = fminf(vneg[i],  sm ? POSINF : w);
          cpos[nt] = fmaxf(cpos[nt], sm ? w : NEGINF);
          cneg[nt] = fminf(cneg[nt], sm ? POSINF : w);
        }
    } else {
      const int colin = nt*16 + m16;   // row updates only on diag tiles
      #pragma unroll
      for (int mt = 0; mt < 2; ++mt)
        #pragma unroll
        for (int r = 0; r < 4; ++r){
          const int i = mt*4 + r;
          const float d2 = fmaf(-2.0f, acc[mt][nt][r], sqi[i] + sqj);
          const float w  = d2 * (pi[i] * pj);
          const bool sm = (labi[i] == labj);
          const bool dg = (colin == wid*32 + mt*16 + quad*4 + r);
          float ep = sm ? w : NEGINF;
          ep = dg ? NEGINF : ep;
          vpos[i] = fmaxf(vpos[i], ep);
          vneg[i] = fminf(vneg[i], sm ? POSINF : w);
        }
    }
  }

  // row states: reduce across 16 col-lanes; guarded atomics (skip sentinels)
  #pragma unroll
  for (int i = 0; i < 8; ++i)
    #pragma unroll
    for (int m = 1; m < 16; m <<= 1){
      vpos[i] = fmaxf(vpos[i], __shfl_xor(vpos[i], m, 16));
      vneg[i] = fminf(vneg[i], __shfl_xor(vneg[i], m, 16));
    }
  if (m16 == 0){
    #pragma unroll
    for (int i = 0; i < 8; ++i){
      const int row = WR0 + (i >> 2)*16 + quad*4 + (i & 3);
      if (vpos[i] > NEGINF) atomicMax(pm + row, encf(vpos[i]));
      if (vneg[i] < POSINF) atomicMax(nm + row, ~encf(vneg[i]));
    }
  }

  if (!diag){
    // col states: reduce across quads, merge waves via LDS, guarded atomics
    #pragma unroll
    for (int nt = 0; nt < 8; ++nt){
      cpos[nt] = fmaxf(cpos[nt], __shfl_xor(cpos[nt], 16));
      cpos[nt] = fmaxf(cpos[nt], __shfl_xor(cpos[nt], 32));
      cneg[nt] = fminf(cneg[nt], __shfl_xor(cneg[nt], 16));
      cneg[nt] = fminf(cneg[nt], __shfl_xor(cneg[nt], 32));
    }
    float* cbP = reinterpret_cast<float*>(Bt);
    float* cbN = cbP + 512;
    __syncthreads();   // Bt ds_reads complete; safe to reuse
    if (quad == 0){
      #pragma unroll
      for (int nt = 0; nt < 8; ++nt){
        cbP[wid*128 + nt*16 + m16] = cpos[nt];
        cbN[wid*128 + nt*16 + m16] = cneg[nt];
      }
    }
    __syncthreads();
    if (tid < 128){
      float P = NEGINF, N = POSINF;
      #pragma unroll
      for (int w = 0; w < 4; ++w){
        P = fmaxf(P, cbP[w*128 + tid]);
        N = fminf(N, cbN[w*128 + tid]);
      }
      if (P > NEGINF) atomicMax(pm + C0 + tid, encf(P));
      if (N < POSINF) atomicMax(nm + C0 + tid, ~encf(N));
    }
  }

  // ---- done protocol + fused finalize (no fences) --------------------------
  __syncthreads();   // implicit s_waitcnt vmcnt(0): all waves' atomics complete
  if (tid == 0)
    s_last = (atomicAdd(done, 1u) == (u32)(NBLK - 1)) ? 1u : 0u;
  __syncthreads();
  if (s_last){
    float lsum = 0.0f, lcnt = 0.0f;
    for (int r = tid; r < NB; r += 256){
      const u32 pe = atomicMax(pm + r, 0u);   // coherent RMW read
      const u32 ne = atomicMax(nm + r, 0u);
      float dp = 0.0f, dn = 0.0f;
      // arccosh(1+t) = log1p(t + sqrt(t*(t+2))), t = 2w clamped at 1e-7
      if (pe){ float t = fmaxf(2.0f * decf(pe),  1e-7f); dp = log1pf(t + sqrtf(t * (t + 2.0f))); }
      if (ne){ float t = fmaxf(2.0f * decf(~ne), 1e-7f); dn = log1pf(t + sqrtf(t * (t + 2.0f))); }
      if (pe && ne){ lsum += fmaxf(dp - dn + 0.5f, 0.0f); lcnt += 1.0f; }
    }
    #pragma unroll
    for (int m = 1; m < 64; m <<= 1){
      lsum += __shfl_xor(lsum, m, 64);
      lcnt += __shfl_xor(lcnt, m, 64);
    }
    if (lane == 0) s_fin[wid] = make_float2(lsum, lcnt);
    __syncthreads();
    if (tid == 0){
      const float S = s_fin[0].x + s_fin[1].x + s_fin[2].x + s_fin[3].x;
      const float C = s_fin[0].y + s_fin[1].y + s_fin[2].y + s_fin[3].y;
      out[0] = (C > 0.0f) ? (S / C) : 0.0f;
    }
  }
}

extern "C" void kernel_launch(void* const* d_in, const int* in_sizes, int n_in,
                              void* d_out, int out_size, void* d_ws, size_t ws_size,
                              hipStream_t stream)
{
  const float* x  = (const float*)d_in[0];
  const int* lab  = (const int*)d_in[1];
  char* ws = (char*)d_ws;
  u32* pm   = (u32*)ws;                       // 32 KB: encf(max pos w), 0 = empty
  u32* nm   = (u32*)(ws + 32*1024);           // 32 KB: ~encf(min neg w), 0 = empty
  u32* done = (u32*)(ws + 64*1024);           // 4 B

  hipMemsetAsync(ws, 0, 64*1024 + 64, stream);
  hipLaunchKernelGGL(fused_k, dim3(NBLK), dim3(256), 0, stream,
                     x, lab, pm, nm, done, (float*)d_out);
}

// Round 7
// 162.131 us; speedup vs baseline: 1.5990x; 1.0177x over previous
//
#include <hip/hip_runtime.h>
#include <hip/hip_bf16.h>

typedef __attribute__((ext_vector_type(8))) __bf16 bf16x8;
typedef __attribute__((ext_vector_type(4))) float f32x4;
typedef unsigned short u16;
typedef unsigned int u32;

#define NB 8192
#define NBLK 2080
#define NEGINF (-__builtin_inff())
#define POSINF (__builtin_inff())
#define ENC_NEGINF 0x007FFFFFu   // encf(-inf)
#define ENC_POSINF 0xFF800000u   // encf(+inf)

__device__ inline u16 f2b(float f){
  __hip_bfloat16 h = __float2bfloat16(f);
  return *reinterpret_cast<u16*>(&h);
}
// monotone float <-> uint encoding (order-preserving incl. +-inf)
__device__ inline u32 encf(float f){
  u32 b = __float_as_uint(f);
  return b ^ (0x80000000u | (u32)(((int)b) >> 31));
}
__device__ inline float decf(u32 u){
  return __uint_as_float(u ^ (0x80000000u | (u32)((~(int)u) >> 31)));
}
__device__ inline f32x4 mfma16(bf16x8 a, bf16x8 b, f32x4 c){
  return __builtin_amdgcn_mfma_f32_16x16x32_bf16(a, b, c, 0, 0, 0);
}

// ---- prep: fp32->bf16, colp=(sq, p, s*p, lab); sentinel init (R3-proven) ---
extern "C" __global__ __launch_bounds__(256)
void prep_k(const float* __restrict__ x, const int* __restrict__ lab,
            u16* __restrict__ xb, float4* __restrict__ colp,
            u32* __restrict__ ppos, u32* __restrict__ pneg,
            u32* __restrict__ done)
{
  const int tid = blockIdx.x * 256 + threadIdx.x;
  const int row = tid >> 5;
  const int sub = tid & 31;
  const float4 v = reinterpret_cast<const float4*>(x)[row * 32 + sub];
  float s = v.x*v.x + v.y*v.y + v.z*v.z + v.w*v.w;
  #pragma unroll
  for (int m = 1; m < 32; m <<= 1) s += __shfl_xor(s, m, 32);
  ushort4 o;
  o.x = f2b(v.x); o.y = f2b(v.y); o.z = f2b(v.z); o.w = f2b(v.w);
  reinterpret_cast<ushort4*>(xb)[row * 32 + sub] = o;
  if (sub == 0){
    const float p = 1.0f / (1.0f - s);
    colp[row] = make_float4(s, p, s * p, __int_as_float(lab[row]));
  }
  if (sub == 1) ppos[row] = ENC_NEGINF;
  if (sub == 2) pneg[row] = ENC_POSINF;
  if (tid == 0) *done = 0u;
}

// ---- main: triangular 128x128 tiles, NO LDS staging (A and B fragments both
// loaded directly from row-major bf16 xb — identical per-lane chunk layout),
// symmetric w = d2*p_i*p_j, R3-proven guarded atomics, R4/R5-proven fence-free
// done-protocol + fused finalize.
extern "C" __global__ __launch_bounds__(256, 2)
void gram_k(const u16* __restrict__ xb, const float4* __restrict__ colp,
            u32* __restrict__ ppos, u32* __restrict__ pneg,
            u32* __restrict__ done, float* __restrict__ out)
{
  __shared__ float cbP[512], cbN[512];   // 4 waves x 128 col partials
  __shared__ u32 s_last;
  __shared__ float2 s_fin[4];

  const int tid  = threadIdx.x;
  const int wid  = tid >> 6;
  const int lane = tid & 63;
  const int m16  = lane & 15;
  const int quad = lane >> 4;

  // triangular decode: g(b)=b*(129-b)/2 (R3/R4/R5-proven)
  int idx = (int)blockIdx.x;
  int bi0 = (int)((129.0f - sqrtf((float)(16641 - 8 * idx))) * 0.5f);
  while ((bi0 + 1) * (129 - (bi0 + 1)) / 2 <= idx) ++bi0;
  while (bi0 * (129 - bi0) / 2 > idx) --bi0;
  const int bi = __builtin_amdgcn_readfirstlane(bi0);
  const int bj = __builtin_amdgcn_readfirstlane(bi0 + (idx - bi0 * (129 - bi0) / 2));
  const bool diag = (bi == bj);
  const int C0  = bj * 128;
  const int WR0 = bi * 128 + wid * 32;

  // A fragments: row (WR0+mt*16+m16), 16B chunk (ks*4+quad)
  bf16x8 afrag[2][4];
  #pragma unroll
  for (int mt = 0; mt < 2; ++mt){
    const u16* arow = xb + (size_t)(WR0 + mt*16 + m16) * 128;
    #pragma unroll
    for (int ks = 0; ks < 4; ++ks)
      afrag[mt][ks] = *reinterpret_cast<const bf16x8*>(arow + ks*32 + quad*8);
  }

  // per-row params (C/D row = quad*4 + r)
  float sqi[8], pi[8]; int labi[8];
  #pragma unroll
  for (int mt = 0; mt < 2; ++mt)
    #pragma unroll
    for (int r = 0; r < 4; ++r){
      const float4 cp = colp[WR0 + mt*16 + quad*4 + r];
      sqi[mt*4+r]  = cp.x;
      pi[mt*4+r]   = cp.y;
      labi[mt*4+r] = __float_as_int(cp.w);
    }
  // per-col params (col = nt*16 + m16)
  float sqj[8], pj[8]; int labj[8];
  #pragma unroll
  for (int nt = 0; nt < 8; ++nt){
    const float4 cp = colp[C0 + nt*16 + m16];
    sqj[nt]  = cp.x;
    pj[nt]   = cp.y;
    labj[nt] = __float_as_int(cp.w);
  }

  // ---- MFMA: B fragments straight from global (same layout as A) ----------
  f32x4 acc[2][8];
  #pragma unroll
  for (int mt = 0; mt < 2; ++mt)
    #pragma unroll
    for (int nt = 0; nt < 8; ++nt){
      f32x4 z = {0.f, 0.f, 0.f, 0.f};
      acc[mt][nt] = z;
    }
  #pragma unroll
  for (int ks = 0; ks < 4; ++ks){
    #pragma unroll
    for (int nt = 0; nt < 8; ++nt){
      const bf16x8 bfrag = *reinterpret_cast<const bf16x8*>(
          xb + (size_t)(C0 + nt*16 + m16) * 128 + ks*32 + quad*8);
      acc[0][nt] = mfma16(afrag[0][ks], bfrag, acc[0][nt]);
      acc[1][nt] = mfma16(afrag[1][ks], bfrag, acc[1][nt]);
    }
  }

  // ---- epilogue: w = (sq_i+sq_j-2g) * p_i * p_j (symmetric) ----------------
  float vpos[8], vneg[8], cpos[8], cneg[8];
  #pragma unroll
  for (int i = 0; i < 8; ++i){
    vpos[i] = NEGINF; vneg[i] = POSINF;
    cpos[i] = NEGINF; cneg[i] = POSINF;
  }
  #pragma unroll
  for (int nt = 0; nt < 8; ++nt){
    const float sj = sqj[nt], pjj = pj[nt];
    const int  lj  = labj[nt];
    if (!diag){
      #pragma unroll
      for (int mt = 0; mt < 2; ++mt)
        #pragma unroll
        for (int r = 0; r < 4; ++r){
          const int i = mt*4 + r;
          const float d2 = fmaf(-2.0f, acc[mt][nt][r], sqi[i] + sj);
          const float w  = (d2 * pi[i]) * pjj;
          const bool sm = (labi[i] == lj);
          const float ep = sm ? w : NEGINF;
          const float en = sm ? POSINF : w;
          vpos[i]  = fmaxf(vpos[i],  ep);
          vneg[i]  = fminf(vneg[i],  en);
          cpos[nt] = fmaxf(cpos[nt], ep);
          cneg[nt] = fminf(cneg[nt], en);
        }
    } else {
      const int colin = nt*16 + m16;   // row updates only on diag tiles
      #pragma unroll
      for (int mt = 0; mt < 2; ++mt)
        #pragma unroll
        for (int r = 0; r < 4; ++r){
          const int i = mt*4 + r;
          const float d2 = fmaf(-2.0f, acc[mt][nt][r], sqi[i] + sj);
          const float w  = (d2 * pi[i]) * pjj;
          const bool sm = (labi[i] == lj);
          const bool dg = (colin == wid*32 + mt*16 + quad*4 + r);
          float ep = sm ? w : NEGINF;
          ep = dg ? NEGINF : ep;
          vpos[i] = fmaxf(vpos[i], ep);
          vneg[i] = fminf(vneg[i], sm ? POSINF : w);
        }
    }
  }

  // row states: reduce across 16 col-lanes; guarded atomics (R3-proven)
  #pragma unroll
  for (int i = 0; i < 8; ++i)
    #pragma unroll
    for (int m = 1; m < 16; m <<= 1){
      vpos[i] = fmaxf(vpos[i], __shfl_xor(vpos[i], m, 16));
      vneg[i] = fminf(vneg[i], __shfl_xor(vneg[i], m, 16));
    }
  if (m16 == 0){
    #pragma unroll
    for (int i = 0; i < 8; ++i){
      const int row = WR0 + (i >> 2)*16 + quad*4 + (i & 3);
      if (vpos[i] > NEGINF) atomicMax(ppos + row, encf(vpos[i]));
      if (vneg[i] < POSINF) atomicMin(pneg + row, encf(vneg[i]));
    }
  }

  if (!diag){
    // col states: reduce across quads (rows), merge waves via LDS, atomics
    #pragma unroll
    for (int nt = 0; nt < 8; ++nt){
      cpos[nt] = fmaxf(cpos[nt], __shfl_xor(cpos[nt], 16));
      cpos[nt] = fmaxf(cpos[nt], __shfl_xor(cpos[nt], 32));
      cneg[nt] = fminf(cneg[nt], __shfl_xor(cneg[nt], 16));
      cneg[nt] = fminf(cneg[nt], __shfl_xor(cneg[nt], 32));
    }
    if (quad == 0){
      #pragma unroll
      for (int nt = 0; nt < 8; ++nt){
        cbP[wid*128 + nt*16 + m16] = cpos[nt];
        cbN[wid*128 + nt*16 + m16] = cneg[nt];
      }
    }
    __syncthreads();
    if (tid < 128){
      float P = NEGINF, N = POSINF;
      #pragma unroll
      for (int w = 0; w < 4; ++w){
        P = fmaxf(P, cbP[w*128 + tid]);
        N = fminf(N, cbN[w*128 + tid]);
      }
      if (P > NEGINF) atomicMax(ppos + C0 + tid, encf(P));
      if (N < POSINF) atomicMin(pneg + C0 + tid, encf(N));
    }
  }

  // ---- done protocol + fused finalize (R4/R5-proven, no fences) ------------
  __syncthreads();   // implicit vmcnt(0) drain: this block's atomics complete
  if (tid == 0)
    s_last = (atomicAdd(done, 1u) == (u32)(NBLK - 1)) ? 1u : 0u;
  __syncthreads();
  if (s_last){
    float lsum = 0.0f, lcnt = 0.0f;
    for (int r = tid; r < NB; r += 256){
      const float up = decf(atomicMax(ppos + r, 0u));          // coherent RMW read
      const float un = decf(atomicMin(pneg + r, 0xFFFFFFFFu)); // coherent RMW read
      const bool hp = (up > NEGINF);
      const bool hn = (un < POSINF);
      float dp = 0.0f, dn = 0.0f;
      // arccosh(1+t) = log1p(t + sqrt(t*(t+2))), t = 2w clamped at 1e-7
      if (hp){ float t = fmaxf(2.0f * up, 1e-7f); dp = log1pf(t + sqrtf(t * (t + 2.0f))); }
      if (hn){ float t = fmaxf(2.0f * un, 1e-7f); dn = log1pf(t + sqrtf(t * (t + 2.0f))); }
      if (hp && hn){ lsum += fmaxf(dp - dn + 0.5f, 0.0f); lcnt += 1.0f; }
    }
    #pragma unroll
    for (int m = 1; m < 64; m <<= 1){
      lsum += __shfl_xor(lsum, m, 64);
      lcnt += __shfl_xor(lcnt, m, 64);
    }
    if (lane == 0) s_fin[wid] = make_float2(lsum, lcnt);
    __syncthreads();
    if (tid == 0){
      const float S = s_fin[0].x + s_fin[1].x + s_fin[2].x + s_fin[3].x;
      const float C = s_fin[0].y + s_fin[1].y + s_fin[2].y + s_fin[3].y;
      out[0] = (C > 0.0f) ? (S / C) : 0.0f;
    }
  }
}

extern "C" void kernel_launch(void* const* d_in, const int* in_sizes, int n_in,
                              void* d_out, int out_size, void* d_ws, size_t ws_size,
                              hipStream_t stream)
{
  const float* x  = (const float*)d_in[0];
  const int* lab  = (const int*)d_in[1];
  char* ws = (char*)d_ws;
  u16*    xb   = (u16*)ws;                                    // 2 MB
  float4* colp = (float4*)(ws + (size_t)2*1024*1024);         // 128 KB
  u32*    ppos = (u32*)(ws + (size_t)2*1024*1024 + 128*1024); // 32 KB
  u32*    pneg = (u32*)(ws + (size_t)2*1024*1024 + 160*1024); // 32 KB
  u32*    done = (u32*)(ws + (size_t)2*1024*1024 + 192*1024); // 4 B

  hipLaunchKernelGGL(prep_k, dim3(1024), dim3(256), 0, stream,
                     x, lab, xb, colp, ppos, pneg, done);
  hipLaunchKernelGGL(gram_k, dim3(NBLK), dim3(256), 0, stream,
                     xb, colp, ppos, pneg, done, (float*)d_out);
}